// Round 1
// baseline (185.728 us; speedup 1.0000x reference)
//
#include <hip/hip_runtime.h>
#include <math.h>

#define H 32
#define S 64
#define K 64
#define B 32

__device__ __forceinline__ float gelu_f(float x) {
    return 0.5f * x * (1.0f + erff(x * 0.70710678118654752440f));
}

// ws layout (floats):
// [0, 2080)        pe (65 x 32)
// [2080, 6176)     wmat (64 x 64) softmax pooling weights
// [6176, 71712)    energies (32 x 64 x 32)
// [71712, 73760)   partials (2048)

__global__ void precompute_kernel(const float* __restrict__ positions,
                                  float* __restrict__ pe,
                                  float* __restrict__ wmat) {
    int tid = threadIdx.x;
    // pe rows 0..64 (only these are used: pe[0] for init, pe[i+1] for steps)
    for (int t = tid; t < 65 * 32; t += 256) {
        int p = t >> 5, c = t & 31;
        int iq = c >> 1;
        double dt = pow(10000.0, (double)(2 * iq) / 32.0);
        float ang = (float)p * (float)dt;   // f32 rounding matches reference
        double v = (c & 1) ? cos((double)ang) : sin((double)ang);
        pe[t] = (float)v;
    }
    // wmat[i][j] = softmax over j<i of positions[j] (row 0 unused -> zeros)
    if (tid < 64) {
        int i = tid;
        if (i == 0) {
            for (int j = 0; j < 64; ++j) wmat[j] = 0.0f;
        } else {
            float m = -1e30f;
            for (int j = 0; j < i; ++j) m = fmaxf(m, positions[j]);
            float s = 0.0f;
            for (int j = 0; j < i; ++j) s += expf(positions[j] - m);
            for (int j = 0; j < i; ++j) wmat[i * 64 + j] = expf(positions[j] - m) / s;
            for (int j = i; j < 64; ++j) wmat[i * 64 + j] = 0.0f;
        }
    }
}

// One block per batch row b: the sequential 64-step k=0 chain.
__global__ __launch_bounds__(256) void chain_kernel(
    const int* __restrict__ neighbor_ids,
    const int* __restrict__ param_indices,
    const float* __restrict__ weights,
    const float* __restrict__ biases,
    const float* __restrict__ node_bias,
    const float* __restrict__ pe,
    const float* __restrict__ wmat,
    float* __restrict__ energies) {
    int b = blockIdx.x;
    int tid = threadIdx.x;
    int d = tid & 31;

    __shared__ float cache[S][H];      // 8KB  - nxt[:,0] history
    __shared__ float wbuf[H * H];      // 4KB  - current W (double-buffered via regs)
    __shared__ float bias_sh[S][H];    // 8KB
    __shared__ float pe_sh[S][H];      // 8KB  - pe rows 1..64
    __shared__ float wmat_sh[S * S];   // 16KB
    __shared__ int idx_sh[S];

    if (tid < S) idx_sh[tid] = param_indices[((size_t)b * S + tid) * K];
    __syncthreads();

    // bulk-preload biases / pe / wmat (all issued up front, one latency)
    for (int r = tid >> 5; r < S; r += 8) {
        bias_sh[r][d] = biases[(size_t)idx_sh[r] * H + d];
        pe_sh[r][d]   = pe[(r + 1) * H + d];
    }
    for (int t = tid; t < S * S; t += 256) wmat_sh[t] = wmat[t];

    // register double-buffer prefetch of W (each thread carries 16B)
    float4 n0 = ((const float4*)(weights + (size_t)idx_sh[0] * (H * H)))[tid];
    float4 n1 = ((const float4*)(weights + (size_t)idx_sh[1] * (H * H)))[tid];

    float init_e = 0.0f;
    if (tid < H) {
        int nid = neighbor_ids[(size_t)b * S * K * 2];  // [b,0,0,0]
        init_e = gelu_f(0.03125f + node_bias[(size_t)nid * H + d] + pe[d]);
    }
    __syncthreads();

    for (int i = 0; i < S; ++i) {
        ((float4*)wbuf)[tid] = n0;     // waits on the load issued 2 steps ago
        __syncthreads();
        n0 = n1;
        if (i + 2 < S) n1 = ((const float4*)(weights + (size_t)idx_sh[i + 2] * (H * H)))[tid];
        if (tid < H) {
            float e;
            if (i == 0) {
                e = init_e;
            } else {
                float acc = 0.0f;
                for (int j = 0; j < i; ++j) acc = fmaf(wmat_sh[i * S + j], cache[j][d], acc);
                e = acc;
            }
            energies[((size_t)b * S + i) * H + d] = e;
            float acc = 0.0f;
            #pragma unroll
            for (int h = 0; h < H; ++h)
                acc = fmaf(__shfl(e, h, 32), wbuf[h * H + d], acc);
            cache[i][d] = gelu_f(acc + bias_sh[i][d] + pe_sh[i][d]);
        }
        __syncthreads();               // protect wbuf before next overwrite
    }
}

// One block per (b,i): all K=64 gathered matvecs + logsumexp.
__global__ __launch_bounds__(256) void big_kernel(
    const int* __restrict__ param_indices,
    const float* __restrict__ weights,
    const float* __restrict__ biases,
    const float* __restrict__ pe,
    const float* __restrict__ energies,
    float* __restrict__ partials) {
    int bi = blockIdx.x;               // b*S + i
    int i = bi & 63;
    int tid = threadIdx.x;
    int half = tid >> 5;               // 0..7 half-waves
    int d = tid & 31;

    __shared__ float e_sh[H];
    __shared__ float pe_sh[H];
    __shared__ float en_sh[K];
    __shared__ int idx_sh[K];

    if (tid < H) {
        e_sh[tid]  = energies[(size_t)bi * H + tid];
        pe_sh[tid] = pe[(i + 1) * H + tid];
    }
    if (tid < K) idx_sh[tid] = param_indices[(size_t)bi * K + tid];
    __syncthreads();

    for (int it = 0; it < 8; ++it) {
        int k = it * 8 + half;
        int idx = idx_sh[k];
        const float* W = weights + (size_t)idx * (H * H);
        float acc = 0.0f;
        #pragma unroll
        for (int h = 0; h < H; ++h) acc = fmaf(e_sh[h], W[h * H + d], acc);
        float val = gelu_f(acc + biases[(size_t)idx * H + d] + pe_sh[d]);
        float ss = val * val;
        #pragma unroll
        for (int m = 16; m; m >>= 1) ss += __shfl_xor(ss, m, 32);
        if (d == 0) en_sh[k] = sqrtf(ss);
    }
    __syncthreads();

    // logsumexp over the 64 norms (wave 0 only)
    if (tid < K) {
        float en = en_sh[tid];
        float m = en;
        #pragma unroll
        for (int mk = 32; mk; mk >>= 1) m = fmaxf(m, __shfl_xor(m, mk, 64));
        float s = expf(en - m);
        #pragma unroll
        for (int mk = 32; mk; mk >>= 1) s += __shfl_xor(s, mk, 64);
        if (tid == 0) partials[bi] = m + logf(s) - en_sh[0];
    }
}

// Deterministic fixed-order reduction of the 2048 partials.
__global__ __launch_bounds__(256) void reduce_kernel(const float* __restrict__ partials,
                                                     float* __restrict__ out) {
    __shared__ float sh[256];
    int tid = threadIdx.x;
    float s = 0.0f;
    for (int j = 0; j < 8; ++j) s += partials[tid + j * 256];
    sh[tid] = s;
    __syncthreads();
    for (int ofs = 128; ofs; ofs >>= 1) {
        if (tid < ofs) sh[tid] += sh[tid + ofs];
        __syncthreads();
    }
    if (tid == 0) out[0] = sh[0] * (1.0f / 2048.0f);
}

extern "C" void kernel_launch(void* const* d_in, const int* in_sizes, int n_in,
                              void* d_out, int out_size, void* d_ws, size_t ws_size,
                              hipStream_t stream) {
    const int*   neighbor_ids  = (const int*)d_in[0];
    const int*   param_indices = (const int*)d_in[1];
    const float* weights       = (const float*)d_in[2];
    const float* biases        = (const float*)d_in[3];
    const float* node_bias     = (const float*)d_in[4];
    const float* positions     = (const float*)d_in[5];

    float* ws       = (float*)d_ws;
    float* pe       = ws;                    // 2080
    float* wmat     = ws + 2080;             // 4096
    float* energies = ws + 6176;             // 65536
    float* partials = ws + 6176 + B * S * H; // 2048

    hipLaunchKernelGGL(precompute_kernel, dim3(1), dim3(256), 0, stream,
                       positions, pe, wmat);
    hipLaunchKernelGGL(chain_kernel, dim3(B), dim3(256), 0, stream,
                       neighbor_ids, param_indices, weights, biases, node_bias,
                       pe, wmat, energies);
    hipLaunchKernelGGL(big_kernel, dim3(B * S), dim3(256), 0, stream,
                       param_indices, weights, biases, pe, energies, partials);
    hipLaunchKernelGGL(reduce_kernel, dim3(1), dim3(256), 0, stream,
                       partials, (float*)d_out);
}

// Round 2
// 177.935 us; speedup vs baseline: 1.0438x; 1.0438x over previous
//
#include <hip/hip_runtime.h>
#include <math.h>

#define H 32
#define S 64
#define K 64
#define B 32

__device__ __forceinline__ float gelu_f(float x) {
    return 0.5f * x * (1.0f + erff(x * 0.70710678118654752440f));
}

// ws layout (floats):
// [0, 2080)              pe (65 x 32)
// [2080, 67616)          energies (32 x 64 x 32)
// [67616, 69664)         partials (2048)

__global__ void precompute_kernel(float* __restrict__ pe) {
    int tid = threadIdx.x;
    for (int t = tid; t < 65 * 32; t += 256) {
        int p = t >> 5, c = t & 31;
        int iq = c >> 1;
        double dt = pow(10000.0, (double)(2 * iq) / 32.0);
        float ang = (float)p * (float)dt;   // f32 rounding matches reference
        double v = (c & 1) ? cos((double)ang) : sin((double)ang);
        pe[t] = (float)v;
    }
}

// One single-wave block per batch row b: the sequential 64-step k=0 chain.
// Online-softmax pooling (no wmat / cache storage), depth-3 W prefetch.
__global__ __launch_bounds__(64) void chain_kernel(
    const int* __restrict__ neighbor_ids,
    const int* __restrict__ param_indices,
    const float* __restrict__ weights,
    const float* __restrict__ biases,
    const float* __restrict__ node_bias,
    const float* __restrict__ pe_g,
    const float* __restrict__ positions,
    float* __restrict__ energies) {
    int b = blockIdx.x;
    int l = threadIdx.x;      // 0..63
    int r = l >> 5;           // row-phase 0/1
    int d = l & 31;           // output column

    __shared__ float wbuf[H * H];        // 4KB current W
    __shared__ float e_sh[H];
    __shared__ float bias_sh[S][H];      // 8KB
    __shared__ float pe_sh[(S + 1) * H]; // 8.3KB
    __shared__ float pos_sh[S];
    __shared__ int idx_sh[S];

    idx_sh[l] = param_indices[((size_t)(b * S + l)) * K];   // k=0 index per step
    pos_sh[l] = positions[l];
    for (int t = l; t < (S + 1) * H; t += 64) pe_sh[t] = pe_g[t];
    __syncthreads();   // single wave: cheap

    for (int t = l; t < S * H; t += 64) {
        int row = t >> 5;
        bias_sh[row][t & 31] = biases[(size_t)idx_sh[row] * H + (t & 31)];
    }

    // depth-3 register prefetch of W (each lane carries 4 x float4 = 64B)
    float4 n0[4], n1[4], n2[4];
    {
        const float4* W0 = (const float4*)(weights + (size_t)idx_sh[0] * (H * H));
        const float4* W1 = (const float4*)(weights + (size_t)idx_sh[1] * (H * H));
        const float4* W2 = (const float4*)(weights + (size_t)idx_sh[2] * (H * H));
        #pragma unroll
        for (int j = 0; j < 4; ++j) { n0[j] = W0[j * 64 + l]; n1[j] = W1[j * 64 + l]; n2[j] = W2[j * 64 + l]; }
    }

    float init_e;
    {
        int nid = neighbor_ids[(size_t)b * S * K * 2];  // [b,0,0,0]
        init_e = gelu_f(0.03125f + node_bias[(size_t)nid * H + d] + pe_sh[d]);
    }
    __syncthreads();

    // online softmax pooling state (per lane, for column d; replicated across r)
    float m = -1e30f, ssum = 0.0f, A = 0.0f, nxtprev = 0.0f;

    for (int i = 0; i < S; ++i) {
        #pragma unroll
        for (int j = 0; j < 4; ++j) ((float4*)wbuf)[j * 64 + l] = n0[j];
        #pragma unroll
        for (int j = 0; j < 4; ++j) { n0[j] = n1[j]; n1[j] = n2[j]; }
        if (i + 3 < S) {
            const float4* Wn = (const float4*)(weights + (size_t)idx_sh[i + 3] * (H * H));
            #pragma unroll
            for (int j = 0; j < 4; ++j) n2[j] = Wn[j * 64 + l];
        }

        float e;
        if (i == 0) {
            e = init_e;
        } else {
            float p = pos_sh[i - 1];
            if (p > m) { float sc = expf(m - p); A *= sc; ssum *= sc; m = p; }
            float w = expf(p - m);
            A = fmaf(w, nxtprev, A);
            ssum += w;
            e = A / ssum;
        }
        if (r == 0) {
            energies[((size_t)(b * S + i)) * H + d] = e;
            e_sh[d] = e;
        }
        __syncthreads();

        float acc = 0.0f;
        #pragma unroll
        for (int hh = 0; hh < 16; ++hh) {
            int h = hh * 2 + r;
            acc = fmaf(e_sh[h], wbuf[h * 32 + d], acc);
        }
        acc += __shfl_xor(acc, 32, 64);
        nxtprev = gelu_f(acc + bias_sh[i][d] + pe_sh[(i + 1) * 32 + d]);
        __syncthreads();   // protect wbuf/e_sh before next overwrite
    }
}

// One block per (b,i): K=64 gathered matvecs + logsumexp.
// Whole-wave float2 matvec: lane = (q=row-phase 0..3, dp=col-pair 0..15).
__global__ __launch_bounds__(256) void big_kernel(
    const int* __restrict__ param_indices,
    const float* __restrict__ weights,
    const float* __restrict__ biases,
    const float* __restrict__ pe_g,
    const float* __restrict__ energies,
    float* __restrict__ partials) {
    int bi = blockIdx.x;               // b*S + i
    int i = bi & 63;
    int tid = threadIdx.x;
    int wave = tid >> 6;               // 0..3
    int lane = tid & 63;
    int q = lane >> 4;                 // 0..3
    int dp = lane & 15;                // column-pair

    __shared__ float e_sh[H];
    __shared__ float en_sh[K];
    __shared__ int idx_sh[K];

    if (tid < H) e_sh[tid] = energies[(size_t)bi * H + tid];
    if (tid < K) idx_sh[tid] = param_indices[(size_t)bi * K + tid];
    __syncthreads();

    float pex = pe_g[(i + 1) * H + 2 * dp];
    float pey = pe_g[(i + 1) * H + 2 * dp + 1];
    float ereg[8];
    #pragma unroll
    for (int hh = 0; hh < 8; ++hh) ereg[hh] = e_sh[hh * 4 + q];

    // 16 matrices per wave, 2 in flight for memory-level parallelism
    for (int it = 0; it < 8; ++it) {
        int ka = wave * 16 + it;
        int kb = ka + 8;
        int ia = idx_sh[ka], ib = idx_sh[kb];
        const float2* Wa = (const float2*)(weights + (size_t)ia * (H * H));
        const float2* Wb = (const float2*)(weights + (size_t)ib * (H * H));
        float axa = 0, aya = 0, axb = 0, ayb = 0;
        #pragma unroll
        for (int hh = 0; hh < 8; ++hh) {
            int h = hh * 4 + q;
            float2 wa = Wa[h * 16 + dp];
            float2 wb = Wb[h * 16 + dp];
            axa = fmaf(ereg[hh], wa.x, axa);
            aya = fmaf(ereg[hh], wa.y, aya);
            axb = fmaf(ereg[hh], wb.x, axb);
            ayb = fmaf(ereg[hh], wb.y, ayb);
        }
        axa += __shfl_xor(axa, 16, 64); aya += __shfl_xor(aya, 16, 64);
        axb += __shfl_xor(axb, 16, 64); ayb += __shfl_xor(ayb, 16, 64);
        axa += __shfl_xor(axa, 32, 64); aya += __shfl_xor(aya, 32, 64);
        axb += __shfl_xor(axb, 32, 64); ayb += __shfl_xor(ayb, 32, 64);
        float2 b2a = *(const float2*)(biases + (size_t)ia * H + 2 * dp);
        float2 b2b = *(const float2*)(biases + (size_t)ib * H + 2 * dp);
        float v0a = gelu_f(axa + b2a.x + pex);
        float v1a = gelu_f(aya + b2a.y + pey);
        float v0b = gelu_f(axb + b2b.x + pex);
        float v1b = gelu_f(ayb + b2b.y + pey);
        float ssa = fmaf(v0a, v0a, v1a * v1a);
        float ssb = fmaf(v0b, v0b, v1b * v1b);
        #pragma unroll
        for (int mk = 8; mk; mk >>= 1) {
            ssa += __shfl_xor(ssa, mk, 64);
            ssb += __shfl_xor(ssb, mk, 64);
        }
        if (lane == 0) { en_sh[ka] = sqrtf(ssa); en_sh[kb] = sqrtf(ssb); }
    }
    __syncthreads();

    // logsumexp over the 64 norms (wave 0 only)
    if (tid < K) {
        float en = en_sh[tid];
        float mm = en;
        #pragma unroll
        for (int mk = 32; mk; mk >>= 1) mm = fmaxf(mm, __shfl_xor(mm, mk, 64));
        float s = expf(en - mm);
        #pragma unroll
        for (int mk = 32; mk; mk >>= 1) s += __shfl_xor(s, mk, 64);
        if (tid == 0) partials[bi] = mm + logf(s) - en_sh[0];
    }
}

// Deterministic fixed-order reduction of the 2048 partials.
__global__ __launch_bounds__(256) void reduce_kernel(const float* __restrict__ partials,
                                                     float* __restrict__ out) {
    __shared__ float sh[256];
    int tid = threadIdx.x;
    float s = 0.0f;
    for (int j = 0; j < 8; ++j) s += partials[tid + j * 256];
    sh[tid] = s;
    __syncthreads();
    for (int ofs = 128; ofs; ofs >>= 1) {
        if (tid < ofs) sh[tid] += sh[tid + ofs];
        __syncthreads();
    }
    if (tid == 0) out[0] = sh[0] * (1.0f / 2048.0f);
}

extern "C" void kernel_launch(void* const* d_in, const int* in_sizes, int n_in,
                              void* d_out, int out_size, void* d_ws, size_t ws_size,
                              hipStream_t stream) {
    const int*   neighbor_ids  = (const int*)d_in[0];
    const int*   param_indices = (const int*)d_in[1];
    const float* weights       = (const float*)d_in[2];
    const float* biases        = (const float*)d_in[3];
    const float* node_bias     = (const float*)d_in[4];
    const float* positions     = (const float*)d_in[5];

    float* ws       = (float*)d_ws;
    float* pe       = ws;                    // 2080
    float* energies = ws + 2080;             // 65536
    float* partials = ws + 2080 + B * S * H; // 2048

    hipLaunchKernelGGL(precompute_kernel, dim3(1), dim3(256), 0, stream, pe);
    hipLaunchKernelGGL(chain_kernel, dim3(B), dim3(64), 0, stream,
                       neighbor_ids, param_indices, weights, biases, node_bias,
                       pe, positions, energies);
    hipLaunchKernelGGL(big_kernel, dim3(B * S), dim3(256), 0, stream,
                       param_indices, weights, biases, pe, energies, partials);
    hipLaunchKernelGGL(reduce_kernel, dim3(1), dim3(256), 0, stream,
                       partials, (float*)d_out);
}